// Round 11
// baseline (412.241 us; speedup 1.0000x reference)
//
#include <hip/hip_runtime.h>
#include <math.h>

#define N_USERS 100000
#define N_ITEMS 200000
#define N_NODES 300000
#define EMB_DIM 64
#define N_EDGES 4000000
#define BATCH   8192
#define EMB_REG 2.5e-05f

#define BUCK_SH 9                       // 512 nodes per bucket
#define BN      512
#define NBUCK   586                     // ceil(300000/512)
#define BSLOT   7424                    // slots per bucket region (mean 6827 + 7 sigma)
#define EPB     8192                    // edges per block (partition kernel)
#define EPT     32                      // edges per thread
#define NBLK_A  489                     // ceil(N_EDGES/EPB)
#define PACK_SH 19                      // t in bits[0:19), hrel in bits[19:28)
#define SCORE_BLOCKS (BATCH / 4)
#define BLOCKS_PER_RANGE 9375

typedef unsigned short u16;
typedef unsigned int   u32;
typedef unsigned char  u8;
typedef __attribute__((ext_vector_type(8))) u16 u16x8;
typedef __attribute__((ext_vector_type(2))) float f32x2;

__device__ __forceinline__ float bf2f(u16 x) {
    u32 u = ((u32)x) << 16;
    return __builtin_bit_cast(float, u);
}
__device__ __forceinline__ u16 f2bf(float f) {
    u32 u = __builtin_bit_cast(u32, f);
    return (u16)((u + 0x7FFFu + ((u >> 16) & 1u)) >> 16);
}

// ---------- prep: mark scored nodes (flags=1), init cursors + counter ----------
// flags[] arrives poisoned to 0xAA (harness re-poisons d_ws before every call),
// which we treat as the cleared state — no memset pass needed.
__global__ void k_prep(const int* __restrict__ users, const int* __restrict__ pos,
                       const int* __restrict__ neg,
                       int* __restrict__ bcur, int* __restrict__ counter,
                       u8* __restrict__ flags) {
    int b = blockIdx.x;
    if (b < 32) {
        int i = b * 256 + threadIdx.x;          // 8192 batch elements
        flags[users[i]] = 1;
        flags[N_USERS + pos[i]] = 1;
        flags[N_USERS + neg[i]] = 1;
    } else {
        for (int j = threadIdx.x; j < NBUCK; j += 256) bcur[j] = j * BSLOT;
        if (threadIdx.x == 0) counter[0] = 0;
    }
}

// ---------- phase A: partition edges into fixed bucket regions (packed ints) ----------
__global__ __launch_bounds__(256) void kA(const int* __restrict__ hh,
                                          const int* __restrict__ tt,
                                          int* __restrict__ bcur, int* __restrict__ gp) {
    __shared__ int sh_cnt[NBUCK];
    __shared__ int sh_base[NBUCK];
    int tid = threadIdx.x;
    for (int j = tid; j < NBUCK; j += 256) sh_cnt[j] = 0;
    __syncthreads();
    int cbase = blockIdx.x * EPB;
    int clen  = min(EPB, N_EDGES - cbase);
    int pk[EPT], bk[EPT];
    #pragma unroll
    for (int j = 0; j < EPT; ++j) {
        int i = j * 256 + tid;
        bk[j] = -1;
        if (i < clen) {
            int h = hh[cbase + i];
            int t = tt[cbase + i];
            int b = h >> BUCK_SH;
            bk[j] = b;
            pk[j] = ((h & (BN - 1)) << PACK_SH) | t;
            atomicAdd(&sh_cnt[b], 1);
        }
    }
    __syncthreads();
    for (int j = tid; j < NBUCK; j += 256) {
        int c = sh_cnt[j];
        sh_base[j] = c ? atomicAdd(&bcur[j], c) : 0;
        sh_cnt[j] = 0;                 // reuse as local cursor
    }
    __syncthreads();
    #pragma unroll
    for (int j = 0; j < EPT; ++j) {
        if (bk[j] >= 0) {
            int r = atomicAdd(&sh_cnt[bk[j]], 1);
            gp[sh_base[bk[j]] + r] = pk[j];
        }
    }
}

// ---------- phase B: per-bucket exact CSR (t-sorted segments) + sde/dinv + fp8 ----------
// Segments are insertion-sorted by tail id so SpMM/score waves sweep the
// source array in ascending order — concurrent waves stay roughly in phase,
// shrinking each XCD's instantaneous L2 working set.
__global__ __launch_bounds__(256) void kB(const int* __restrict__ bcur,
                                          int* __restrict__ gp,
                                          int2* __restrict__ sde, float* __restrict__ dinv,
                                          const float* __restrict__ uemb,
                                          const float* __restrict__ iemb,
                                          u8* __restrict__ e0s8) {
    __shared__ int   ncnt[BN];
    __shared__ int   noff[BN];
    __shared__ float sdv[BN];
    __shared__ int   slots[BSLOT];
    int b = blockIdx.x;
    int node0 = b << BUCK_SH;
    int nn = min(BN, N_NODES - node0);
    int base = b * BSLOT;
    int count = bcur[b] - base;
    int tid = threadIdx.x;
    for (int j = tid; j < BN; j += 256) ncnt[j] = 0;
    __syncthreads();
    for (int i = tid; i < count; i += 256)
        atomicAdd(&ncnt[gp[base + i] >> PACK_SH], 1);
    __syncthreads();
    if (tid < 64) {                       // exclusive scan over 512 node counts
        int lane = tid, carry = 0;
        #pragma unroll
        for (int b0 = 0; b0 < BN; b0 += 64) {
            int idx = b0 + lane;
            int v = ncnt[idx];
            int incl = v;
            #pragma unroll
            for (int d = 1; d < 64; d <<= 1) {
                int u = __shfl_up(incl, d, 64);
                if (lane >= d) incl += u;
            }
            noff[idx] = carry + incl - v;
            carry += __shfl(incl, 63, 64);
        }
    }
    __syncthreads();
    for (int j = tid; j < nn; j += 256) {
        int c = ncnt[j];
        float dv = c > 0 ? rsqrtf((float)c) : 0.0f;
        sde[node0 + j]  = make_int2(base + noff[j], c);
        dinv[node0 + j] = dv;
        sdv[j] = dv;
    }
    __syncthreads();
    for (int j = tid; j < BN; j += 256) ncnt[j] = noff[j];   // ncnt = cursor
    __syncthreads();
    for (int i = tid; i < count; i += 256) {     // scatter t by node into LDS
        int p = gp[base + i];
        int r = atomicAdd(&ncnt[p >> PACK_SH], 1);
        slots[r] = p & ((1 << PACK_SH) - 1);
    }
    __syncthreads();
    // insertion-sort each node's segment by t (one thread per node, ~deg^2 ops)
    for (int j = tid; j < nn; j += 256) {
        int s = noff[j], e = ncnt[j];             // ncnt now holds segment end
        for (int i = s + 1; i < e; ++i) {
            int v = slots[i];
            int k = i - 1;
            while (k >= s && slots[k] > v) { slots[k + 1] = slots[k]; --k; }
            slots[k + 1] = v;
        }
    }
    __syncthreads();
    for (int i = tid; i < count; i += 256)       // coalesced flush (aliases edges_t)
        gp[base + i] = slots[i];
    // fused: e0s8[v] = Q(dinv[v] * e0[v]) for this bucket's nodes
    for (int i = tid; i < nn * 8; i += 256) {
        int j = i >> 3;
        float sc = sdv[j];
        int gnode = node0 + j;
        size_t ebase = (size_t)gnode * EMB_DIM + (size_t)(i & 7) * 8;
        const size_t UELEMS = (size_t)N_USERS * EMB_DIM;
        const float* src = (ebase < UELEMS) ? uemb + ebase : iemb + (ebase - UELEMS);
        float4 a  = ((const float4*)src)[0];
        float4 c4 = ((const float4*)src)[1];
        u32 w0 = __builtin_amdgcn_cvt_pk_fp8_f32(sc * a.x,  sc * a.y,  0,  false);
        w0 = __builtin_amdgcn_cvt_pk_fp8_f32(sc * a.z,  sc * a.w,  w0, true);
        u32 w1 = __builtin_amdgcn_cvt_pk_fp8_f32(sc * c4.x, sc * c4.y, 0,  false);
        w1 = __builtin_amdgcn_cvt_pk_fp8_f32(sc * c4.z, sc * c4.w, w1, true);
        uint2 o; o.x = w0; o.y = w1;
        ((uint2*)e0s8)[(size_t)gnode * 8 + (i & 7)] = o;
    }
}

// ---------- layer-1 SpMM (fp8 pre-scaled rows): one wave per node ----------
// emb1 = dh * Σ gathered + self(fp32)
// outputs: fp8 Q(dh*emb1) always; bf16 emb1 only for scored (flags==1) nodes
__global__ void k_spmm1(const int2* __restrict__ sde,
                        const int* __restrict__ et,
                        const float* __restrict__ dinv,
                        const u8* __restrict__ src8,
                        const float* __restrict__ uemb, const float* __restrict__ iemb,
                        const u8* __restrict__ flags,
                        u16* __restrict__ dstb, u8* __restrict__ dst8) {
    int b = blockIdx.x;   // grid = 75000 = 8 * 9375, XCD-range congruent
    int node = ((b & 7) * BLOCKS_PER_RANGE + (b >> 3)) * 4 + (threadIdx.x >> 6);
    int lane = threadIdx.x & 63;
    int grp = lane >> 3;       // 8 concurrent edges
    int sl  = lane & 7;        // 8-dim slot within the 64-dim row
    int2 se = sde[node];
    int s = se.x, ne = se.y;
    float dh = dinv[node];
    int ets = (lane < ne) ? et[s + lane] : 0;    // coalesced segment load
    float acc[8] = {0.f, 0.f, 0.f, 0.f, 0.f, 0.f, 0.f, 0.f};
    int lim = ne < 64 ? ne : 64;
    for (int j = grp; j < lim; j += 8) {
        int t = __shfl(ets, j, 64);
        uint2 d8 = ((const uint2*)(src8 + (size_t)t * EMB_DIM))[sl];
        f32x2 p0 = __builtin_amdgcn_cvt_pk_f32_fp8(d8.x, false);
        f32x2 p1 = __builtin_amdgcn_cvt_pk_f32_fp8(d8.x, true);
        f32x2 p2 = __builtin_amdgcn_cvt_pk_f32_fp8(d8.y, false);
        f32x2 p3 = __builtin_amdgcn_cvt_pk_f32_fp8(d8.y, true);
        acc[0] += p0.x; acc[1] += p0.y;
        acc[2] += p1.x; acc[3] += p1.y;
        acc[4] += p2.x; acc[5] += p2.y;
        acc[6] += p3.x; acc[7] += p3.y;
    }
    for (int i = s + 64 + grp; i < s + ne; i += 8) {  // rare deg>64 tail
        int t = et[i];
        uint2 d8 = ((const uint2*)(src8 + (size_t)t * EMB_DIM))[sl];
        f32x2 p0 = __builtin_amdgcn_cvt_pk_f32_fp8(d8.x, false);
        f32x2 p1 = __builtin_amdgcn_cvt_pk_f32_fp8(d8.x, true);
        f32x2 p2 = __builtin_amdgcn_cvt_pk_f32_fp8(d8.y, false);
        f32x2 p3 = __builtin_amdgcn_cvt_pk_f32_fp8(d8.y, true);
        acc[0] += p0.x; acc[1] += p0.y;
        acc[2] += p1.x; acc[3] += p1.y;
        acc[4] += p2.x; acc[5] += p2.y;
        acc[6] += p3.x; acc[7] += p3.y;
    }
    #pragma unroll
    for (int m = 8; m <= 32; m <<= 1) {
        #pragma unroll
        for (int k = 0; k < 8; ++k)
            acc[k] += __shfl_xor(acc[k], m, 64);
    }
    if (grp == 0) {
        const float* srow = (node < N_USERS)
            ? uemb + (size_t)node * EMB_DIM
            : iemb + (size_t)(node - N_USERS) * EMB_DIM;
        float4 a = ((const float4*)srow)[sl * 2];
        float4 c = ((const float4*)srow)[sl * 2 + 1];
        float v[8];
        v[0] = dh * acc[0] + a.x; v[1] = dh * acc[1] + a.y;
        v[2] = dh * acc[2] + a.z; v[3] = dh * acc[3] + a.w;
        v[4] = dh * acc[4] + c.x; v[5] = dh * acc[5] + c.y;
        v[6] = dh * acc[6] + c.z; v[7] = dh * acc[7] + c.w;
        u32 w0 = __builtin_amdgcn_cvt_pk_fp8_f32(dh * v[0], dh * v[1], 0, false);
        w0 = __builtin_amdgcn_cvt_pk_fp8_f32(dh * v[2], dh * v[3], w0, true);
        u32 w1 = __builtin_amdgcn_cvt_pk_fp8_f32(dh * v[4], dh * v[5], 0, false);
        w1 = __builtin_amdgcn_cvt_pk_fp8_f32(dh * v[6], dh * v[7], w1, true);
        uint2 ow; ow.x = w0; ow.y = w1;
        ((uint2*)(dst8 + (size_t)node * EMB_DIM))[sl] = ow;
        if (flags[node] == 1) {          // scored node: bf16 copy for k_score
            u16x8 o;
            o.s0 = f2bf(v[0]); o.s1 = f2bf(v[1]); o.s2 = f2bf(v[2]); o.s3 = f2bf(v[3]);
            o.s4 = f2bf(v[4]); o.s5 = f2bf(v[5]); o.s6 = f2bf(v[6]); o.s7 = f2bf(v[7]);
            ((u16x8*)(dstb + (size_t)node * EMB_DIM))[sl] = o;
        }
    }
}

// ---------- scoring (fused layer-2 rows + fused final reduction) ----------
__global__ void k_score(const int* __restrict__ users, const int* __restrict__ pos,
                        const int* __restrict__ neg,
                        const float* __restrict__ uemb, const float* __restrict__ iemb,
                        const u16* __restrict__ emb1b, const u8* __restrict__ emb1s8,
                        const int2* __restrict__ sde, const int* __restrict__ et,
                        const float* __restrict__ dinv,
                        float* __restrict__ pmf, float* __restrict__ psq,
                        int* __restrict__ counter, float* __restrict__ out) {
    __shared__ float smf[4], ssq[4];
    __shared__ int sdone;
    int gid = blockIdx.x * blockDim.x + threadIdx.x;
    int b = gid >> 6;
    int d = gid & 63;
    int w = threadIdx.x >> 6;
    int u  = users[b];
    int pi = pos[b];
    int ni = neg[b];
    int nodes[3];
    nodes[0] = u; nodes[1] = N_USERS + pi; nodes[2] = N_USERS + ni;
    float pre[3];
    pre[0] = uemb[(size_t)u * EMB_DIM + d];
    pre[1] = iemb[(size_t)pi * EMB_DIM + d];
    pre[2] = iemb[(size_t)ni * EMB_DIM + d];
    int s0[3], ne[3], ets[3];
    float dv[3];
    #pragma unroll
    for (int k = 0; k < 3; ++k) {
        int v = nodes[k];
        int2 se = sde[v];
        s0[k] = se.x; ne[k] = se.y;
        dv[k] = dinv[v];
        ets[k] = (d < ne[k]) ? et[se.x + d] : 0;
    }
    float a[3];
    #pragma unroll
    for (int k = 0; k < 3; ++k) {
        float ac = 0.f;
        int lim = ne[k] < 64 ? ne[k] : 64;
        for (int j = 0; j < lim; ++j) {
            int t = __shfl(ets[k], j, 64);
            u32 byte = emb1s8[(size_t)t * EMB_DIM + d];
            ac += __builtin_amdgcn_cvt_f32_fp8(byte, 0);
        }
        for (int i = s0[k] + 64; i < s0[k] + ne[k]; ++i) {   // rare deg>64 tail
            int t = et[i];
            u32 byte = emb1s8[(size_t)t * EMB_DIM + d];
            ac += __builtin_amdgcn_cvt_f32_fp8(byte, 0);
        }
        a[k] = pre[k] + 2.0f * bf2f(emb1b[(size_t)nodes[k] * EMB_DIM + d]) + dv[k] * ac;
    }
    float ps = a[0] * a[1];
    float ns = a[0] * a[2];
    float sq = pre[0] * pre[0] + pre[1] * pre[1] + pre[2] * pre[2];
    #pragma unroll
    for (int off2 = 32; off2 > 0; off2 >>= 1) {
        ps += __shfl_down(ps, off2, 64);
        ns += __shfl_down(ns, off2, 64);
        sq += __shfl_down(sq, off2, 64);
    }
    if (d == 0) {
        float x  = ns - ps;
        smf[w] = fmaxf(x, 0.0f) + log1pf(expf(-fabsf(x)));
        ssq[w] = sq;
    }
    __syncthreads();
    if (threadIdx.x == 0) {
        pmf[blockIdx.x] = smf[0] + smf[1] + smf[2] + smf[3];
        psq[blockIdx.x] = ssq[0] + ssq[1] + ssq[2] + ssq[3];
        __threadfence();                                   // release partials
        sdone = (atomicAdd(counter, 1) == SCORE_BLOCKS - 1);
    }
    __syncthreads();
    if (sdone) {                                           // last block reduces
        __threadfence();                                   // acquire partials
        int tid = threadIdx.x;
        float mf = 0.f, s2 = 0.f;
        #pragma unroll
        for (int i = 0; i < SCORE_BLOCKS / 256; ++i) {
            mf += pmf[tid + i * 256];
            s2 += psq[tid + i * 256];
        }
        #pragma unroll
        for (int off2 = 32; off2 > 0; off2 >>= 1) {
            mf += __shfl_down(mf, off2, 64);
            s2 += __shfl_down(s2, off2, 64);
        }
        if ((tid & 63) == 0) { smf[tid >> 6] = mf; ssq[tid >> 6] = s2; }
        __syncthreads();
        if (tid == 0) {
            out[0] = (smf[0] + smf[1] + smf[2] + smf[3]) * (1.0f / BATCH);
            out[1] = EMB_REG * (ssq[0] + ssq[1] + ssq[2] + ssq[3]);
        }
    }
}

extern "C" void kernel_launch(void* const* d_in, const int* in_sizes, int n_in,
                              void* d_out, int out_size, void* d_ws, size_t ws_size,
                              hipStream_t stream) {
    const float* uemb  = (const float*)d_in[0];
    const float* iemb  = (const float*)d_in[1];
    const int*   all_h = (const int*)d_in[2];
    const int*   all_t = (const int*)d_in[3];
    const int*   users = (const int*)d_in[4];
    const int*   pos   = (const int*)d_in[5];
    const int*   neg   = (const int*)d_in[6];
    float* out = (float*)d_out;

    // workspace layout (int units)
    int*   ws      = (int*)d_ws;
    float* dinv    = (float*)ws;                  // 300,032
    int2*  sde     = (int2*)(ws + 300032);        // 600,064 ints
    int*   bcur    = ws + 900096;                 // 1024
    u8*    flags   = (u8*)(ws + 901120);          // 75,008 ints (300,032 B)
    float* pmf     = (float*)(ws + 976128);       // 2048
    float* psq     = (float*)(ws + 978176);       // 2048
    int*   counter = ws + 980224;                 // 1024
    int*   gp      = ws + 981248;                 // 586*7424 = 4,350,464
    u8*    e0s8    = (u8*)(ws + 5331712);         // 4.8M ints (19.2 MB)
    u8*    emb1s8  = (u8*)(ws + 10131712);        // 4.8M ints
    u16*   emb1b   = (u16*)(ws + 14931712);       // 9.6M ints (38.4 MB)

    k_prep <<<33, 256, 0, stream>>>(users, pos, neg, bcur, counter, flags);
    kA     <<<NBLK_A, 256, 0, stream>>>(all_h, all_t, bcur, gp);
    kB     <<<NBUCK, 256, 0, stream>>>(bcur, gp, sde, dinv, uemb, iemb, e0s8);

    // layer 1 (all nodes): emb1 = A*Q(dinv·e0) + e0
    k_spmm1<<<N_NODES / 4, 256, 0, stream>>>(sde, gp, dinv, e0s8, uemb, iemb,
                                             flags, emb1b, emb1s8);

    // scoring with fused on-the-fly layer-2 rows + fused final reduction
    k_score<<<SCORE_BLOCKS, 256, 0, stream>>>(users, pos, neg, uemb, iemb,
                                              emb1b, emb1s8, sde, gp, dinv,
                                              pmf, psq, counter, out);
}

// Round 12
// 372.971 us; speedup vs baseline: 1.1053x; 1.1053x over previous
//
#include <hip/hip_runtime.h>
#include <math.h>

#define N_USERS 100000
#define N_ITEMS 200000
#define N_NODES 300000
#define EMB_DIM 64
#define N_EDGES 4000000
#define BATCH   8192
#define EMB_REG 2.5e-05f

#define BUCK_SH 9                       // 512 nodes per bucket
#define BN      512
#define NBUCK   586                     // ceil(300000/512)
#define BSLOT   7424                    // slots per bucket region (mean 6827 + 7 sigma)
#define EPB     8192                    // edges per block (partition kernel)
#define EPT     32                      // edges per thread
#define NBLK_A  489                     // ceil(N_EDGES/EPB)
#define PACK_SH 19                      // t in bits[0:19), hrel in bits[19:28)
#define SCORE_BLOCKS (BATCH / 4)
#define BLOCKS_PER_RANGE 9375

typedef unsigned short u16;
typedef unsigned int   u32;
typedef unsigned char  u8;
typedef __attribute__((ext_vector_type(8))) u16 u16x8;
typedef __attribute__((ext_vector_type(2))) float f32x2;

__device__ __forceinline__ float bf2f(u16 x) {
    u32 u = ((u32)x) << 16;
    return __builtin_bit_cast(float, u);
}
__device__ __forceinline__ u16 f2bf(float f) {
    u32 u = __builtin_bit_cast(u32, f);
    return (u16)((u + 0x7FFFu + ((u >> 16) & 1u)) >> 16);
}

// ---------- prep: mark scored nodes (flags=1), init cursors + counter ----------
// flags[] arrives poisoned to 0xAA (harness re-poisons d_ws before every call),
// which we treat as the cleared state — no memset pass needed.
__global__ void k_prep(const int* __restrict__ users, const int* __restrict__ pos,
                       const int* __restrict__ neg,
                       int* __restrict__ bcur, int* __restrict__ counter,
                       u8* __restrict__ flags) {
    int b = blockIdx.x;
    if (b < 32) {
        int i = b * 256 + threadIdx.x;          // 8192 batch elements
        flags[users[i]] = 1;
        flags[N_USERS + pos[i]] = 1;
        flags[N_USERS + neg[i]] = 1;
    } else {
        for (int j = threadIdx.x; j < NBUCK; j += 256) bcur[j] = j * BSLOT;
        if (threadIdx.x == 0) counter[0] = 0;
    }
}

// ---------- phase A: partition edges into fixed bucket regions (packed ints) ----------
__global__ __launch_bounds__(256) void kA(const int* __restrict__ hh,
                                          const int* __restrict__ tt,
                                          int* __restrict__ bcur, int* __restrict__ gp) {
    __shared__ int sh_cnt[NBUCK];
    __shared__ int sh_base[NBUCK];
    int tid = threadIdx.x;
    for (int j = tid; j < NBUCK; j += 256) sh_cnt[j] = 0;
    __syncthreads();
    int cbase = blockIdx.x * EPB;
    int clen  = min(EPB, N_EDGES - cbase);
    int pk[EPT], bk[EPT];
    #pragma unroll
    for (int j = 0; j < EPT; ++j) {
        int i = j * 256 + tid;
        bk[j] = -1;
        if (i < clen) {
            int h = hh[cbase + i];
            int t = tt[cbase + i];
            int b = h >> BUCK_SH;
            bk[j] = b;
            pk[j] = ((h & (BN - 1)) << PACK_SH) | t;
            atomicAdd(&sh_cnt[b], 1);
        }
    }
    __syncthreads();
    for (int j = tid; j < NBUCK; j += 256) {
        int c = sh_cnt[j];
        sh_base[j] = c ? atomicAdd(&bcur[j], c) : 0;
        sh_cnt[j] = 0;                 // reuse as local cursor
    }
    __syncthreads();
    #pragma unroll
    for (int j = 0; j < EPT; ++j) {
        if (bk[j] >= 0) {
            int r = atomicAdd(&sh_cnt[bk[j]], 1);
            gp[sh_base[bk[j]] + r] = pk[j];
        }
    }
}

// ---------- phase B: per-bucket exact CSR + sde/dinv + fp8 conversion ----------
__global__ __launch_bounds__(256) void kB(const int* __restrict__ bcur,
                                          int* __restrict__ gp,
                                          int2* __restrict__ sde, float* __restrict__ dinv,
                                          const float* __restrict__ uemb,
                                          const float* __restrict__ iemb,
                                          u8* __restrict__ e0s8) {
    __shared__ int   ncnt[BN];
    __shared__ int   noff[BN];
    __shared__ float sdv[BN];
    __shared__ int   slots[BSLOT];
    int b = blockIdx.x;
    int node0 = b << BUCK_SH;
    int nn = min(BN, N_NODES - node0);
    int base = b * BSLOT;
    int count = bcur[b] - base;
    int tid = threadIdx.x;
    for (int j = tid; j < BN; j += 256) ncnt[j] = 0;
    __syncthreads();
    for (int i = tid; i < count; i += 256)
        atomicAdd(&ncnt[gp[base + i] >> PACK_SH], 1);
    __syncthreads();
    if (tid < 64) {                       // exclusive scan over 512 node counts
        int lane = tid, carry = 0;
        #pragma unroll
        for (int b0 = 0; b0 < BN; b0 += 64) {
            int idx = b0 + lane;
            int v = ncnt[idx];
            int incl = v;
            #pragma unroll
            for (int d = 1; d < 64; d <<= 1) {
                int u = __shfl_up(incl, d, 64);
                if (lane >= d) incl += u;
            }
            noff[idx] = carry + incl - v;
            carry += __shfl(incl, 63, 64);
        }
    }
    __syncthreads();
    for (int j = tid; j < nn; j += 256) {
        int c = ncnt[j];
        float dv = c > 0 ? rsqrtf((float)c) : 0.0f;
        sde[node0 + j]  = make_int2(base + noff[j], c);
        dinv[node0 + j] = dv;
        sdv[j] = dv;
    }
    __syncthreads();
    for (int j = tid; j < BN; j += 256) ncnt[j] = noff[j];   // ncnt = cursor
    __syncthreads();
    for (int i = tid; i < count; i += 256) {     // scatter t by node into LDS
        int p = gp[base + i];
        int r = atomicAdd(&ncnt[p >> PACK_SH], 1);
        slots[r] = p & ((1 << PACK_SH) - 1);
    }
    __syncthreads();
    for (int i = tid; i < count; i += 256)       // coalesced flush (aliases edges_t)
        gp[base + i] = slots[i];
    // fused: e0s8[v] = Q(dinv[v] * e0[v]) for this bucket's nodes
    for (int i = tid; i < nn * 8; i += 256) {
        int j = i >> 3;
        float sc = sdv[j];
        int gnode = node0 + j;
        size_t ebase = (size_t)gnode * EMB_DIM + (size_t)(i & 7) * 8;
        const size_t UELEMS = (size_t)N_USERS * EMB_DIM;
        const float* src = (ebase < UELEMS) ? uemb + ebase : iemb + (ebase - UELEMS);
        float4 a  = ((const float4*)src)[0];
        float4 c4 = ((const float4*)src)[1];
        u32 w0 = __builtin_amdgcn_cvt_pk_fp8_f32(sc * a.x,  sc * a.y,  0,  false);
        w0 = __builtin_amdgcn_cvt_pk_fp8_f32(sc * a.z,  sc * a.w,  w0, true);
        u32 w1 = __builtin_amdgcn_cvt_pk_fp8_f32(sc * c4.x, sc * c4.y, 0,  false);
        w1 = __builtin_amdgcn_cvt_pk_fp8_f32(sc * c4.z, sc * c4.w, w1, true);
        uint2 o; o.x = w0; o.y = w1;
        ((uint2*)e0s8)[(size_t)gnode * 8 + (i & 7)] = o;
    }
}

// ---------- layer-1 SpMM (fp8 pre-scaled rows): one wave per node ----------
// emb1 = dh * Σ gathered + self(fp32)
// outputs: fp8 Q(dh*emb1) always; bf16 emb1 only for scored (flags==1) nodes
__global__ void k_spmm1(const int2* __restrict__ sde,
                        const int* __restrict__ et,
                        const float* __restrict__ dinv,
                        const u8* __restrict__ src8,
                        const float* __restrict__ uemb, const float* __restrict__ iemb,
                        const u8* __restrict__ flags,
                        u16* __restrict__ dstb, u8* __restrict__ dst8) {
    int b = blockIdx.x;   // grid = 75000 = 8 * 9375, XCD-range congruent
    int node = ((b & 7) * BLOCKS_PER_RANGE + (b >> 3)) * 4 + (threadIdx.x >> 6);
    int lane = threadIdx.x & 63;
    int grp = lane >> 3;       // 8 concurrent edges
    int sl  = lane & 7;        // 8-dim slot within the 64-dim row
    int2 se = sde[node];
    int s = se.x, ne = se.y;
    float dh = dinv[node];
    int ets = (lane < ne) ? et[s + lane] : 0;    // coalesced segment load
    float acc[8] = {0.f, 0.f, 0.f, 0.f, 0.f, 0.f, 0.f, 0.f};
    int lim = ne < 64 ? ne : 64;
    for (int j = grp; j < lim; j += 8) {
        int t = __shfl(ets, j, 64);
        uint2 d8 = ((const uint2*)(src8 + (size_t)t * EMB_DIM))[sl];
        f32x2 p0 = __builtin_amdgcn_cvt_pk_f32_fp8(d8.x, false);
        f32x2 p1 = __builtin_amdgcn_cvt_pk_f32_fp8(d8.x, true);
        f32x2 p2 = __builtin_amdgcn_cvt_pk_f32_fp8(d8.y, false);
        f32x2 p3 = __builtin_amdgcn_cvt_pk_f32_fp8(d8.y, true);
        acc[0] += p0.x; acc[1] += p0.y;
        acc[2] += p1.x; acc[3] += p1.y;
        acc[4] += p2.x; acc[5] += p2.y;
        acc[6] += p3.x; acc[7] += p3.y;
    }
    for (int i = s + 64 + grp; i < s + ne; i += 8) {  // rare deg>64 tail
        int t = et[i];
        uint2 d8 = ((const uint2*)(src8 + (size_t)t * EMB_DIM))[sl];
        f32x2 p0 = __builtin_amdgcn_cvt_pk_f32_fp8(d8.x, false);
        f32x2 p1 = __builtin_amdgcn_cvt_pk_f32_fp8(d8.x, true);
        f32x2 p2 = __builtin_amdgcn_cvt_pk_f32_fp8(d8.y, false);
        f32x2 p3 = __builtin_amdgcn_cvt_pk_f32_fp8(d8.y, true);
        acc[0] += p0.x; acc[1] += p0.y;
        acc[2] += p1.x; acc[3] += p1.y;
        acc[4] += p2.x; acc[5] += p2.y;
        acc[6] += p3.x; acc[7] += p3.y;
    }
    #pragma unroll
    for (int m = 8; m <= 32; m <<= 1) {
        #pragma unroll
        for (int k = 0; k < 8; ++k)
            acc[k] += __shfl_xor(acc[k], m, 64);
    }
    if (grp == 0) {
        const float* srow = (node < N_USERS)
            ? uemb + (size_t)node * EMB_DIM
            : iemb + (size_t)(node - N_USERS) * EMB_DIM;
        float4 a = ((const float4*)srow)[sl * 2];
        float4 c = ((const float4*)srow)[sl * 2 + 1];
        float v[8];
        v[0] = dh * acc[0] + a.x; v[1] = dh * acc[1] + a.y;
        v[2] = dh * acc[2] + a.z; v[3] = dh * acc[3] + a.w;
        v[4] = dh * acc[4] + c.x; v[5] = dh * acc[5] + c.y;
        v[6] = dh * acc[6] + c.z; v[7] = dh * acc[7] + c.w;
        u32 w0 = __builtin_amdgcn_cvt_pk_fp8_f32(dh * v[0], dh * v[1], 0, false);
        w0 = __builtin_amdgcn_cvt_pk_fp8_f32(dh * v[2], dh * v[3], w0, true);
        u32 w1 = __builtin_amdgcn_cvt_pk_fp8_f32(dh * v[4], dh * v[5], 0, false);
        w1 = __builtin_amdgcn_cvt_pk_fp8_f32(dh * v[6], dh * v[7], w1, true);
        uint2 ow; ow.x = w0; ow.y = w1;
        ((uint2*)(dst8 + (size_t)node * EMB_DIM))[sl] = ow;
        if (flags[node] == 1) {          // scored node: bf16 copy for k_score
            u16x8 o;
            o.s0 = f2bf(v[0]); o.s1 = f2bf(v[1]); o.s2 = f2bf(v[2]); o.s3 = f2bf(v[3]);
            o.s4 = f2bf(v[4]); o.s5 = f2bf(v[5]); o.s6 = f2bf(v[6]); o.s7 = f2bf(v[7]);
            ((u16x8*)(dstb + (size_t)node * EMB_DIM))[sl] = o;
        }
    }
}

// ---------- scoring (fused layer-2 rows, interleaved gathers, fused reduction) ----------
__global__ void k_score(const int* __restrict__ users, const int* __restrict__ pos,
                        const int* __restrict__ neg,
                        const float* __restrict__ uemb, const float* __restrict__ iemb,
                        const u16* __restrict__ emb1b, const u8* __restrict__ emb1s8,
                        const int2* __restrict__ sde, const int* __restrict__ et,
                        const float* __restrict__ dinv,
                        float* __restrict__ pmf, float* __restrict__ psq,
                        int* __restrict__ counter, float* __restrict__ out) {
    __shared__ float smf[4], ssq[4];
    __shared__ int sdone;
    int gid = blockIdx.x * blockDim.x + threadIdx.x;
    int b = gid >> 6;
    int d = gid & 63;
    int w = threadIdx.x >> 6;
    int u  = users[b];
    int pi = pos[b];
    int ni = neg[b];
    int nodes[3];
    nodes[0] = u; nodes[1] = N_USERS + pi; nodes[2] = N_USERS + ni;
    float pre[3];
    pre[0] = uemb[(size_t)u * EMB_DIM + d];
    pre[1] = iemb[(size_t)pi * EMB_DIM + d];
    pre[2] = iemb[(size_t)ni * EMB_DIM + d];
    int s0[3], ne[3], ets[3];
    float dv[3];
    #pragma unroll
    for (int k = 0; k < 3; ++k) {
        int v = nodes[k];
        int2 se = sde[v];
        s0[k] = se.x; ne[k] = se.y;
        dv[k] = dinv[v];
        ets[k] = (d < ne[k]) ? et[se.x + d] : 0;
    }
    // interleaved gathers over the 3 segments: 3 independent loads in flight
    // per iteration (latency-bound loop -> 3x MLP vs sequential segments)
    float ac[3] = {0.f, 0.f, 0.f};
    int lim[3];
    #pragma unroll
    for (int k = 0; k < 3; ++k) lim[k] = ne[k] < 64 ? ne[k] : 64;
    int limmax = lim[0] > lim[1] ? lim[0] : lim[1];
    if (lim[2] > limmax) limmax = lim[2];
    for (int j = 0; j < limmax; ++j) {
        #pragma unroll
        for (int k = 0; k < 3; ++k) {
            if (j < lim[k]) {               // wave-uniform branch
                int t = __shfl(ets[k], j, 64);
                ac[k] += __builtin_amdgcn_cvt_f32_fp8(emb1s8[(size_t)t * EMB_DIM + d], 0);
            }
        }
    }
    #pragma unroll
    for (int k = 0; k < 3; ++k) {           // rare deg>64 tails
        for (int i = s0[k] + 64; i < s0[k] + ne[k]; ++i) {
            int t = et[i];
            ac[k] += __builtin_amdgcn_cvt_f32_fp8(emb1s8[(size_t)t * EMB_DIM + d], 0);
        }
    }
    float a[3];
    #pragma unroll
    for (int k = 0; k < 3; ++k)
        a[k] = pre[k] + 2.0f * bf2f(emb1b[(size_t)nodes[k] * EMB_DIM + d]) + dv[k] * ac[k];
    float ps = a[0] * a[1];
    float ns = a[0] * a[2];
    float sq = pre[0] * pre[0] + pre[1] * pre[1] + pre[2] * pre[2];
    #pragma unroll
    for (int off2 = 32; off2 > 0; off2 >>= 1) {
        ps += __shfl_down(ps, off2, 64);
        ns += __shfl_down(ns, off2, 64);
        sq += __shfl_down(sq, off2, 64);
    }
    if (d == 0) {
        float x  = ns - ps;
        smf[w] = fmaxf(x, 0.0f) + log1pf(expf(-fabsf(x)));
        ssq[w] = sq;
    }
    __syncthreads();
    if (threadIdx.x == 0) {
        pmf[blockIdx.x] = smf[0] + smf[1] + smf[2] + smf[3];
        psq[blockIdx.x] = ssq[0] + ssq[1] + ssq[2] + ssq[3];
        __threadfence();                                   // release partials
        sdone = (atomicAdd(counter, 1) == SCORE_BLOCKS - 1);
    }
    __syncthreads();
    if (sdone) {                                           // last block reduces
        __threadfence();                                   // acquire partials
        int tid = threadIdx.x;
        float mf = 0.f, s2 = 0.f;
        #pragma unroll
        for (int i = 0; i < SCORE_BLOCKS / 256; ++i) {
            mf += pmf[tid + i * 256];
            s2 += psq[tid + i * 256];
        }
        #pragma unroll
        for (int off2 = 32; off2 > 0; off2 >>= 1) {
            mf += __shfl_down(mf, off2, 64);
            s2 += __shfl_down(s2, off2, 64);
        }
        if ((tid & 63) == 0) { smf[tid >> 6] = mf; ssq[tid >> 6] = s2; }
        __syncthreads();
        if (tid == 0) {
            out[0] = (smf[0] + smf[1] + smf[2] + smf[3]) * (1.0f / BATCH);
            out[1] = EMB_REG * (ssq[0] + ssq[1] + ssq[2] + ssq[3]);
        }
    }
}

extern "C" void kernel_launch(void* const* d_in, const int* in_sizes, int n_in,
                              void* d_out, int out_size, void* d_ws, size_t ws_size,
                              hipStream_t stream) {
    const float* uemb  = (const float*)d_in[0];
    const float* iemb  = (const float*)d_in[1];
    const int*   all_h = (const int*)d_in[2];
    const int*   all_t = (const int*)d_in[3];
    const int*   users = (const int*)d_in[4];
    const int*   pos   = (const int*)d_in[5];
    const int*   neg   = (const int*)d_in[6];
    float* out = (float*)d_out;

    // workspace layout (int units)
    int*   ws      = (int*)d_ws;
    float* dinv    = (float*)ws;                  // 300,032
    int2*  sde     = (int2*)(ws + 300032);        // 600,064 ints
    int*   bcur    = ws + 900096;                 // 1024
    u8*    flags   = (u8*)(ws + 901120);          // 75,008 ints (300,032 B)
    float* pmf     = (float*)(ws + 976128);       // 2048
    float* psq     = (float*)(ws + 978176);       // 2048
    int*   counter = ws + 980224;                 // 1024
    int*   gp      = ws + 981248;                 // 586*7424 = 4,350,464
    u8*    e0s8    = (u8*)(ws + 5331712);         // 4.8M ints (19.2 MB)
    u8*    emb1s8  = (u8*)(ws + 10131712);        // 4.8M ints
    u16*   emb1b   = (u16*)(ws + 14931712);       // 9.6M ints (38.4 MB)

    k_prep <<<33, 256, 0, stream>>>(users, pos, neg, bcur, counter, flags);
    kA     <<<NBLK_A, 256, 0, stream>>>(all_h, all_t, bcur, gp);
    kB     <<<NBUCK, 256, 0, stream>>>(bcur, gp, sde, dinv, uemb, iemb, e0s8);

    // layer 1 (all nodes): emb1 = A*Q(dinv·e0) + e0
    k_spmm1<<<N_NODES / 4, 256, 0, stream>>>(sde, gp, dinv, e0s8, uemb, iemb,
                                             flags, emb1b, emb1s8);

    // scoring with fused on-the-fly layer-2 rows + fused final reduction
    k_score<<<SCORE_BLOCKS, 256, 0, stream>>>(users, pos, neg, uemb, iemb,
                                              emb1b, emb1s8, sde, gp, dinv,
                                              pmf, psq, counter, out);
}

// Round 13
// 362.062 us; speedup vs baseline: 1.1386x; 1.0301x over previous
//
#include <hip/hip_runtime.h>
#include <math.h>

#define N_USERS 100000
#define N_ITEMS 200000
#define N_NODES 300000
#define EMB_DIM 64
#define N_EDGES 4000000
#define BATCH   8192
#define EMB_REG 2.5e-05f

#define BUCK_SH 9                       // 512 nodes per bucket
#define BN      512
#define NBUCK   586                     // ceil(300000/512)
#define BSLOT   7424                    // slots per bucket region (mean 6827 + 7 sigma)
#define EPB     8192                    // edges per block (partition kernel)
#define EPT     16                      // edges per thread (512-thread blocks)
#define NBLK_A  489                     // ceil(N_EDGES/EPB)
#define PACK_SH 19                      // t in bits[0:19), hrel in bits[19:28)
#define SCORE_BLOCKS (BATCH / 4)
#define BLOCKS_PER_RANGE 9375

typedef unsigned short u16;
typedef unsigned int   u32;
typedef unsigned char  u8;
typedef __attribute__((ext_vector_type(8))) u16 u16x8;
typedef __attribute__((ext_vector_type(2))) float f32x2;

__device__ __forceinline__ float bf2f(u16 x) {
    u32 u = ((u32)x) << 16;
    return __builtin_bit_cast(float, u);
}
__device__ __forceinline__ u16 f2bf(float f) {
    u32 u = __builtin_bit_cast(u32, f);
    return (u16)((u + 0x7FFFu + ((u >> 16) & 1u)) >> 16);
}

// ---------- prep: mark scored nodes (flags=1), init cursors + counter ----------
// flags[] arrives poisoned to 0xAA (harness re-poisons d_ws before every call),
// which we treat as the cleared state — no memset pass needed.
__global__ void k_prep(const int* __restrict__ users, const int* __restrict__ pos,
                       const int* __restrict__ neg,
                       int* __restrict__ bcur, int* __restrict__ counter,
                       u8* __restrict__ flags) {
    int b = blockIdx.x;
    if (b < 32) {
        int i = b * 256 + threadIdx.x;          // 8192 batch elements
        flags[users[i]] = 1;
        flags[N_USERS + pos[i]] = 1;
        flags[N_USERS + neg[i]] = 1;
    } else {
        for (int j = threadIdx.x; j < NBUCK; j += 256) bcur[j] = j * BSLOT;
        if (threadIdx.x == 0) counter[0] = 0;
    }
}

// ---------- phase A: partition edges into fixed bucket regions (packed ints) ----------
// 512-thread blocks: 489 blocks * 256 was ~25% occupancy (nothing to hide the
// 48 MB stream + LDS-atomic latency behind); 512 doubles waves/CU.
__global__ __launch_bounds__(512) void kA(const int* __restrict__ hh,
                                          const int* __restrict__ tt,
                                          int* __restrict__ bcur, int* __restrict__ gp) {
    __shared__ int sh_cnt[NBUCK];
    __shared__ int sh_base[NBUCK];
    int tid = threadIdx.x;
    for (int j = tid; j < NBUCK; j += 512) sh_cnt[j] = 0;
    __syncthreads();
    int cbase = blockIdx.x * EPB;
    int clen  = min(EPB, N_EDGES - cbase);
    int pk[EPT], bk[EPT];
    #pragma unroll
    for (int j = 0; j < EPT; ++j) {
        int i = j * 512 + tid;
        bk[j] = -1;
        if (i < clen) {
            int h = hh[cbase + i];
            int t = tt[cbase + i];
            int b = h >> BUCK_SH;
            bk[j] = b;
            pk[j] = ((h & (BN - 1)) << PACK_SH) | t;
            atomicAdd(&sh_cnt[b], 1);
        }
    }
    __syncthreads();
    for (int j = tid; j < NBUCK; j += 512) {
        int c = sh_cnt[j];
        sh_base[j] = c ? atomicAdd(&bcur[j], c) : 0;
        sh_cnt[j] = 0;                 // reuse as local cursor
    }
    __syncthreads();
    #pragma unroll
    for (int j = 0; j < EPT; ++j) {
        if (bk[j] >= 0) {
            int r = atomicAdd(&sh_cnt[bk[j]], 1);
            gp[sh_base[bk[j]] + r] = pk[j];
        }
    }
}

// ---------- phase B: per-bucket exact CSR + sde/dinv + fp8 conversion ----------
__global__ __launch_bounds__(256) void kB(const int* __restrict__ bcur,
                                          int* __restrict__ gp,
                                          int2* __restrict__ sde, float* __restrict__ dinv,
                                          const float* __restrict__ uemb,
                                          const float* __restrict__ iemb,
                                          u8* __restrict__ e0s8) {
    __shared__ int   ncnt[BN];
    __shared__ int   noff[BN];
    __shared__ float sdv[BN];
    __shared__ int   slots[BSLOT];
    int b = blockIdx.x;
    int node0 = b << BUCK_SH;
    int nn = min(BN, N_NODES - node0);
    int base = b * BSLOT;
    int count = bcur[b] - base;
    int tid = threadIdx.x;
    for (int j = tid; j < BN; j += 256) ncnt[j] = 0;
    __syncthreads();
    for (int i = tid; i < count; i += 256)
        atomicAdd(&ncnt[gp[base + i] >> PACK_SH], 1);
    __syncthreads();
    if (tid < 64) {                       // exclusive scan over 512 node counts
        int lane = tid, carry = 0;
        #pragma unroll
        for (int b0 = 0; b0 < BN; b0 += 64) {
            int idx = b0 + lane;
            int v = ncnt[idx];
            int incl = v;
            #pragma unroll
            for (int d = 1; d < 64; d <<= 1) {
                int u = __shfl_up(incl, d, 64);
                if (lane >= d) incl += u;
            }
            noff[idx] = carry + incl - v;
            carry += __shfl(incl, 63, 64);
        }
    }
    __syncthreads();
    for (int j = tid; j < nn; j += 256) {
        int c = ncnt[j];
        float dv = c > 0 ? rsqrtf((float)c) : 0.0f;
        sde[node0 + j]  = make_int2(base + noff[j], c);
        dinv[node0 + j] = dv;
        sdv[j] = dv;
    }
    __syncthreads();
    for (int j = tid; j < BN; j += 256) ncnt[j] = noff[j];   // ncnt = cursor
    __syncthreads();
    for (int i = tid; i < count; i += 256) {     // scatter t by node into LDS
        int p = gp[base + i];
        int r = atomicAdd(&ncnt[p >> PACK_SH], 1);
        slots[r] = p & ((1 << PACK_SH) - 1);
    }
    __syncthreads();
    for (int i = tid; i < count; i += 256)       // coalesced flush (aliases edges_t)
        gp[base + i] = slots[i];
    // fused: e0s8[v] = Q(dinv[v] * e0[v]) for this bucket's nodes
    for (int i = tid; i < nn * 8; i += 256) {
        int j = i >> 3;
        float sc = sdv[j];
        int gnode = node0 + j;
        size_t ebase = (size_t)gnode * EMB_DIM + (size_t)(i & 7) * 8;
        const size_t UELEMS = (size_t)N_USERS * EMB_DIM;
        const float* src = (ebase < UELEMS) ? uemb + ebase : iemb + (ebase - UELEMS);
        float4 a  = ((const float4*)src)[0];
        float4 c4 = ((const float4*)src)[1];
        u32 w0 = __builtin_amdgcn_cvt_pk_fp8_f32(sc * a.x,  sc * a.y,  0,  false);
        w0 = __builtin_amdgcn_cvt_pk_fp8_f32(sc * a.z,  sc * a.w,  w0, true);
        u32 w1 = __builtin_amdgcn_cvt_pk_fp8_f32(sc * c4.x, sc * c4.y, 0,  false);
        w1 = __builtin_amdgcn_cvt_pk_fp8_f32(sc * c4.z, sc * c4.w, w1, true);
        uint2 o; o.x = w0; o.y = w1;
        ((uint2*)e0s8)[(size_t)gnode * 8 + (i & 7)] = o;
    }
}

// ---------- layer-1 SpMM (fp8 pre-scaled rows): one wave per node ----------
// emb1 = dh * Σ gathered + self(fp32)
// outputs: fp8 Q(dh*emb1) always; bf16 emb1 only for scored (flags==1) nodes
__global__ void k_spmm1(const int2* __restrict__ sde,
                        const int* __restrict__ et,
                        const float* __restrict__ dinv,
                        const u8* __restrict__ src8,
                        const float* __restrict__ uemb, const float* __restrict__ iemb,
                        const u8* __restrict__ flags,
                        u16* __restrict__ dstb, u8* __restrict__ dst8) {
    int b = blockIdx.x;   // grid = 75000 = 8 * 9375, XCD-range congruent
    int node = ((b & 7) * BLOCKS_PER_RANGE + (b >> 3)) * 4 + (threadIdx.x >> 6);
    int lane = threadIdx.x & 63;
    int grp = lane >> 3;       // 8 concurrent edges
    int sl  = lane & 7;        // 8-dim slot within the 64-dim row
    int2 se = sde[node];
    int s = se.x, ne = se.y;
    float dh = dinv[node];
    int ets = (lane < ne) ? et[s + lane] : 0;    // coalesced segment load
    float acc[8] = {0.f, 0.f, 0.f, 0.f, 0.f, 0.f, 0.f, 0.f};
    int lim = ne < 64 ? ne : 64;
    for (int j = grp; j < lim; j += 8) {
        int t = __shfl(ets, j, 64);
        uint2 d8 = ((const uint2*)(src8 + (size_t)t * EMB_DIM))[sl];
        f32x2 p0 = __builtin_amdgcn_cvt_pk_f32_fp8(d8.x, false);
        f32x2 p1 = __builtin_amdgcn_cvt_pk_f32_fp8(d8.x, true);
        f32x2 p2 = __builtin_amdgcn_cvt_pk_f32_fp8(d8.y, false);
        f32x2 p3 = __builtin_amdgcn_cvt_pk_f32_fp8(d8.y, true);
        acc[0] += p0.x; acc[1] += p0.y;
        acc[2] += p1.x; acc[3] += p1.y;
        acc[4] += p2.x; acc[5] += p2.y;
        acc[6] += p3.x; acc[7] += p3.y;
    }
    for (int i = s + 64 + grp; i < s + ne; i += 8) {  // rare deg>64 tail
        int t = et[i];
        uint2 d8 = ((const uint2*)(src8 + (size_t)t * EMB_DIM))[sl];
        f32x2 p0 = __builtin_amdgcn_cvt_pk_f32_fp8(d8.x, false);
        f32x2 p1 = __builtin_amdgcn_cvt_pk_f32_fp8(d8.x, true);
        f32x2 p2 = __builtin_amdgcn_cvt_pk_f32_fp8(d8.y, false);
        f32x2 p3 = __builtin_amdgcn_cvt_pk_f32_fp8(d8.y, true);
        acc[0] += p0.x; acc[1] += p0.y;
        acc[2] += p1.x; acc[3] += p1.y;
        acc[4] += p2.x; acc[5] += p2.y;
        acc[6] += p3.x; acc[7] += p3.y;
    }
    #pragma unroll
    for (int m = 8; m <= 32; m <<= 1) {
        #pragma unroll
        for (int k = 0; k < 8; ++k)
            acc[k] += __shfl_xor(acc[k], m, 64);
    }
    if (grp == 0) {
        const float* srow = (node < N_USERS)
            ? uemb + (size_t)node * EMB_DIM
            : iemb + (size_t)(node - N_USERS) * EMB_DIM;
        float4 a = ((const float4*)srow)[sl * 2];
        float4 c = ((const float4*)srow)[sl * 2 + 1];
        float v[8];
        v[0] = dh * acc[0] + a.x; v[1] = dh * acc[1] + a.y;
        v[2] = dh * acc[2] + a.z; v[3] = dh * acc[3] + a.w;
        v[4] = dh * acc[4] + c.x; v[5] = dh * acc[5] + c.y;
        v[6] = dh * acc[6] + c.z; v[7] = dh * acc[7] + c.w;
        u32 w0 = __builtin_amdgcn_cvt_pk_fp8_f32(dh * v[0], dh * v[1], 0, false);
        w0 = __builtin_amdgcn_cvt_pk_fp8_f32(dh * v[2], dh * v[3], w0, true);
        u32 w1 = __builtin_amdgcn_cvt_pk_fp8_f32(dh * v[4], dh * v[5], 0, false);
        w1 = __builtin_amdgcn_cvt_pk_fp8_f32(dh * v[6], dh * v[7], w1, true);
        uint2 ow; ow.x = w0; ow.y = w1;
        ((uint2*)(dst8 + (size_t)node * EMB_DIM))[sl] = ow;
        if (flags[node] == 1) {          // scored node: bf16 copy for k_score
            u16x8 o;
            o.s0 = f2bf(v[0]); o.s1 = f2bf(v[1]); o.s2 = f2bf(v[2]); o.s3 = f2bf(v[3]);
            o.s4 = f2bf(v[4]); o.s5 = f2bf(v[5]); o.s6 = f2bf(v[6]); o.s7 = f2bf(v[7]);
            ((u16x8*)(dstb + (size_t)node * EMB_DIM))[sl] = o;
        }
    }
}

// ---------- scoring (fused layer-2 rows, SEQUENTIAL gathers, fused reduction) ----------
// Sequential per-segment loops: loads across j iterations are independent (only
// a shfl feeds the address), so the HW already pipelines them — r12's manual
// interleave only added branch/issue overhead (+35 us, reverted).
__global__ void k_score(const int* __restrict__ users, const int* __restrict__ pos,
                        const int* __restrict__ neg,
                        const float* __restrict__ uemb, const float* __restrict__ iemb,
                        const u16* __restrict__ emb1b, const u8* __restrict__ emb1s8,
                        const int2* __restrict__ sde, const int* __restrict__ et,
                        const float* __restrict__ dinv,
                        float* __restrict__ pmf, float* __restrict__ psq,
                        int* __restrict__ counter, float* __restrict__ out) {
    __shared__ float smf[4], ssq[4];
    __shared__ int sdone;
    int gid = blockIdx.x * blockDim.x + threadIdx.x;
    int b = gid >> 6;
    int d = gid & 63;
    int w = threadIdx.x >> 6;
    int u  = users[b];
    int pi = pos[b];
    int ni = neg[b];
    int nodes[3];
    nodes[0] = u; nodes[1] = N_USERS + pi; nodes[2] = N_USERS + ni;
    float pre[3];
    pre[0] = uemb[(size_t)u * EMB_DIM + d];
    pre[1] = iemb[(size_t)pi * EMB_DIM + d];
    pre[2] = iemb[(size_t)ni * EMB_DIM + d];
    int s0[3], ne[3], ets[3];
    float dv[3];
    #pragma unroll
    for (int k = 0; k < 3; ++k) {
        int v = nodes[k];
        int2 se = sde[v];
        s0[k] = se.x; ne[k] = se.y;
        dv[k] = dinv[v];
        ets[k] = (d < ne[k]) ? et[se.x + d] : 0;
    }
    float a[3];
    #pragma unroll
    for (int k = 0; k < 3; ++k) {
        float ac = 0.f;
        int lim = ne[k] < 64 ? ne[k] : 64;
        for (int j = 0; j < lim; ++j) {
            int t = __shfl(ets[k], j, 64);
            ac += __builtin_amdgcn_cvt_f32_fp8(emb1s8[(size_t)t * EMB_DIM + d], 0);
        }
        for (int i = s0[k] + 64; i < s0[k] + ne[k]; ++i) {   // rare deg>64 tail
            int t = et[i];
            ac += __builtin_amdgcn_cvt_f32_fp8(emb1s8[(size_t)t * EMB_DIM + d], 0);
        }
        a[k] = pre[k] + 2.0f * bf2f(emb1b[(size_t)nodes[k] * EMB_DIM + d]) + dv[k] * ac;
    }
    float ps = a[0] * a[1];
    float ns = a[0] * a[2];
    float sq = pre[0] * pre[0] + pre[1] * pre[1] + pre[2] * pre[2];
    #pragma unroll
    for (int off2 = 32; off2 > 0; off2 >>= 1) {
        ps += __shfl_down(ps, off2, 64);
        ns += __shfl_down(ns, off2, 64);
        sq += __shfl_down(sq, off2, 64);
    }
    if (d == 0) {
        float x  = ns - ps;
        smf[w] = fmaxf(x, 0.0f) + log1pf(expf(-fabsf(x)));
        ssq[w] = sq;
    }
    __syncthreads();
    if (threadIdx.x == 0) {
        pmf[blockIdx.x] = smf[0] + smf[1] + smf[2] + smf[3];
        psq[blockIdx.x] = ssq[0] + ssq[1] + ssq[2] + ssq[3];
        __threadfence();                                   // release partials
        sdone = (atomicAdd(counter, 1) == SCORE_BLOCKS - 1);
    }
    __syncthreads();
    if (sdone) {                                           // last block reduces
        __threadfence();                                   // acquire partials
        int tid = threadIdx.x;
        float mf = 0.f, s2 = 0.f;
        #pragma unroll
        for (int i = 0; i < SCORE_BLOCKS / 256; ++i) {
            mf += pmf[tid + i * 256];
            s2 += psq[tid + i * 256];
        }
        #pragma unroll
        for (int off2 = 32; off2 > 0; off2 >>= 1) {
            mf += __shfl_down(mf, off2, 64);
            s2 += __shfl_down(s2, off2, 64);
        }
        if ((tid & 63) == 0) { smf[tid >> 6] = mf; ssq[tid >> 6] = s2; }
        __syncthreads();
        if (tid == 0) {
            out[0] = (smf[0] + smf[1] + smf[2] + smf[3]) * (1.0f / BATCH);
            out[1] = EMB_REG * (ssq[0] + ssq[1] + ssq[2] + ssq[3]);
        }
    }
}

extern "C" void kernel_launch(void* const* d_in, const int* in_sizes, int n_in,
                              void* d_out, int out_size, void* d_ws, size_t ws_size,
                              hipStream_t stream) {
    const float* uemb  = (const float*)d_in[0];
    const float* iemb  = (const float*)d_in[1];
    const int*   all_h = (const int*)d_in[2];
    const int*   all_t = (const int*)d_in[3];
    const int*   users = (const int*)d_in[4];
    const int*   pos   = (const int*)d_in[5];
    const int*   neg   = (const int*)d_in[6];
    float* out = (float*)d_out;

    // workspace layout (int units)
    int*   ws      = (int*)d_ws;
    float* dinv    = (float*)ws;                  // 300,032
    int2*  sde     = (int2*)(ws + 300032);        // 600,064 ints
    int*   bcur    = ws + 900096;                 // 1024
    u8*    flags   = (u8*)(ws + 901120);          // 75,008 ints (300,032 B)
    float* pmf     = (float*)(ws + 976128);       // 2048
    float* psq     = (float*)(ws + 978176);       // 2048
    int*   counter = ws + 980224;                 // 1024
    int*   gp      = ws + 981248;                 // 586*7424 = 4,350,464
    u8*    e0s8    = (u8*)(ws + 5331712);         // 4.8M ints (19.2 MB)
    u8*    emb1s8  = (u8*)(ws + 10131712);        // 4.8M ints
    u16*   emb1b   = (u16*)(ws + 14931712);       // 9.6M ints (38.4 MB)

    k_prep <<<33, 256, 0, stream>>>(users, pos, neg, bcur, counter, flags);
    kA     <<<NBLK_A, 512, 0, stream>>>(all_h, all_t, bcur, gp);
    kB     <<<NBUCK, 256, 0, stream>>>(bcur, gp, sde, dinv, uemb, iemb, e0s8);

    // layer 1 (all nodes): emb1 = A*Q(dinv·e0) + e0
    k_spmm1<<<N_NODES / 4, 256, 0, stream>>>(sde, gp, dinv, e0s8, uemb, iemb,
                                             flags, emb1b, emb1s8);

    // scoring with fused on-the-fly layer-2 rows + fused final reduction
    k_score<<<SCORE_BLOCKS, 256, 0, stream>>>(users, pos, neg, uemb, iemb,
                                              emb1b, emb1s8, sde, gp, dinv,
                                              pmf, psq, counter, out);
}